// Round 11
// baseline (264.950 us; speedup 1.0000x reference)
//
#include <hip/hip_runtime.h>
#include <cstdint>

#define BB 4
#define NN 4096
#define CCH 256

typedef __attribute__((ext_vector_type(8))) short bf16x8;
typedef __attribute__((ext_vector_type(4))) float f32x4;

__device__ __forceinline__ unsigned short bf16rn(float f){
  unsigned u = __float_as_uint(f);
  unsigned r = u + 0x7FFFu + ((u>>16)&1u);
  return (unsigned short)(r>>16);
}
__device__ __forceinline__ float bf16tof(unsigned short h){
  return __uint_as_float(((unsigned)h)<<16);
}
__device__ __forceinline__ void gl_lds16(const void* g, void* l){
  __builtin_amdgcn_global_load_lds(
    (const __attribute__((address_space(1))) void*)g,
    (__attribute__((address_space(3))) void*)l, 16, 0, 0);
}

// ---- prep: split x -> xs [16384][768] bf16 (hi | lo | hi) ----
__global__ __launch_bounds__(256) void prep_x(
    const float* __restrict__ x, unsigned short* __restrict__ xs)
{
  const int stride = gridDim.x * 256;
  for (int idx = blockIdx.x*256 + threadIdx.x; idx < 16384*64; idx += stride){
    const int r = idx >> 6, c4 = (idx & 63) * 4;
    float4 u = *(const float4*)(x + (size_t)r*256 + c4);
    ushort4 h, l;
    h.x=bf16rn(u.x); l.x=bf16rn(u.x - bf16tof(h.x));
    h.y=bf16rn(u.y); l.y=bf16rn(u.y - bf16tof(h.y));
    h.z=bf16rn(u.z); l.z=bf16rn(u.z - bf16tof(h.z));
    h.w=bf16rn(u.w); l.w=bf16rn(u.w - bf16tof(h.w));
    unsigned short* row = xs + (size_t)r*768;
    *(ushort4*)(row + c4)       = h;
    *(ushort4*)(row + 256 + c4) = l;
    *(ushort4*)(row + 512 + c4) = h;
  }
}

// ---- prep: weights -> Wt [512][768] bf16 (hi | hi | lo) ----
__global__ __launch_bounds__(256) void prep_w(
    const float* __restrict__ W1, const float* __restrict__ W2,
    const float* __restrict__ Wa, unsigned short* __restrict__ Wt)
{
  const int n = blockIdx.x;      // 512
  const int k = threadIdx.x;     // 256
  float w = (n < 128) ? W1[(size_t)k*128 + n]
          : (n < 256) ? W2[(size_t)k*128 + (n-128)]
                      : Wa[(size_t)k*256 + (n-256)];
  unsigned short h = bf16rn(w);
  unsigned short l = bf16rn(w - bf16tof(h));
  unsigned short* row = Wt + (size_t)n*768;
  row[k] = h; row[256+k] = h; row[512+k] = l;
}

// ---- fused projection GEMM: 64x128 tile, K=768, single-buffer, XCD-swizzled ----
__global__ __launch_bounds__(256) void proj_mfma(
    const unsigned short* __restrict__ xs, const unsigned short* __restrict__ Wt,
    const float* __restrict__ b1, const float* __restrict__ a1,
    const float* __restrict__ b2, const float* __restrict__ a2,
    const float* __restrict__ ba, const float* __restrict__ aa,
    unsigned short* __restrict__ e1x, unsigned short* __restrict__ e2x,
    float* __restrict__ Vf)
{
  __shared__ __align__(16) short As[64*64];
  __shared__ __align__(16) short Bs[128*64];
  const int t = threadIdx.x;
  const int bid = blockIdx.y * 4 + blockIdx.x;
  const int W = (bid & 7) * 128 + (bid >> 3);
  const int bx = W & 3, by = W >> 2;
  const int m0 = by*64, n0 = bx*128;
  const int wid = t>>6, lane = t&63;
  const int wr = wid>>1, wc = wid&1;
  const int fr = lane&15, fq = lane>>4;
  const int r32 = t>>3, seg = t&7;

  const unsigned short* ap = xs + (size_t)m0*768;
  const unsigned short* bp = Wt + (size_t)n0*768;

  f32x4 acc[2][4];
#pragma unroll
  for (int m=0;m<2;m++)
#pragma unroll
    for (int n=0;n<4;n++) acc[m][n] = (f32x4){0.f,0.f,0.f,0.f};

#pragma unroll
  for (int s=0;s<12;s++){
    const int kk = s*64;
#pragma unroll
    for (int i=0;i<2;i++){
      const int rowL = r32 + i*32;
      const int sw = (seg ^ (rowL & 7)) * 8;
      gl_lds16(ap + (size_t)rowL*768 + kk + sw, &As[rowL*64 + seg*8]);
    }
#pragma unroll
    for (int i=0;i<4;i++){
      const int rowL = r32 + i*32;
      const int sw = (seg ^ (rowL & 7)) * 8;
      gl_lds16(bp + (size_t)rowL*768 + kk + sw, &Bs[rowL*64 + seg*8]);
    }
    __syncthreads();
    bf16x8 af[2][2], bf[4][2];
#pragma unroll
    for (int m=0;m<2;m++){
      const int ar_ = wr*32 + m*16 + fr;
#pragma unroll
      for (int ks=0;ks<2;ks++)
        af[m][ks] = *(const bf16x8*)&As[ar_*64 + (((ks*4+fq) ^ (ar_&7))*8)];
    }
#pragma unroll
    for (int n=0;n<4;n++){
      const int br_ = wc*64 + n*16 + fr;
#pragma unroll
      for (int ks=0;ks<2;ks++)
        bf[n][ks] = *(const bf16x8*)&Bs[br_*64 + (((ks*4+fq) ^ (br_&7))*8)];
    }
#pragma unroll
    for (int m=0;m<2;m++)
#pragma unroll
      for (int n=0;n<4;n++)
#pragma unroll
        for (int ks=0;ks<2;ks++)
          acc[m][n] = __builtin_amdgcn_mfma_f32_16x16x32_bf16(af[m][ks], bf[n][ks], acc[m][n], 0,0,0);
    __syncthreads();
  }

  if (bx < 2){
    const float* bb = bx ? b2 : b1;
    const float al = bx ? a2[0] : a1[0];
    unsigned short* ex = bx ? e2x : e1x;
#pragma unroll
    for (int m=0;m<2;m++){
#pragma unroll
      for (int n=0;n<4;n++){
        const int c = wc*64 + n*16 + fr;
        const float bias = bb[c];
#pragma unroll
        for (int reg=0;reg<4;reg++){
          const size_t r = (size_t)(m0 + wr*32 + m*16 + fq*4 + reg);
          float u = acc[m][n][reg] + bias;
          u = u >= 0.f ? u : al*u;
          unsigned short h = bf16rn(u);
          unsigned short l = bf16rn(u - bf16tof(h));
          if (bx == 0){            // e1x: [h | l | h]
            ex[r*384 + c] = h; ex[r*384 + 128 + c] = l; ex[r*384 + 256 + c] = h;
          } else {                 // e2x: [h | h | l]
            ex[r*384 + c] = h; ex[r*384 + 128 + c] = h; ex[r*384 + 256 + c] = l;
          }
        }
      }
    }
  } else {
    const float al = aa[0];
#pragma unroll
    for (int m=0;m<2;m++){
#pragma unroll
      for (int n=0;n<4;n++){
        const int c = (bx-2)*128 + wc*64 + n*16 + fr;
        const float bias = ba[c];
#pragma unroll
        for (int reg=0;reg<4;reg++){
          const size_t r = (size_t)(m0 + wr*32 + m*16 + fq*4 + reg);
          float u = acc[m][n][reg] + bias;
          Vf[r*CCH + c] = u >= 0.f ? u : al*u;
        }
      }
    }
  }
}

// ---- fused flash QK^T + exact sparsemax + sparse PV + residual ----
// One block = 64 rows of one batch; iterates 32 column-tiles of 128.
// Exactness: support subset {s > runningmax-1} (tau >= finalmax-1, max monotone).
__global__ __launch_bounds__(256) void flash_spv(
    const unsigned short* __restrict__ e1x, const unsigned short* __restrict__ e2x,
    const float* __restrict__ Vf, const float* __restrict__ xr,
    float* __restrict__ out)
{
  __shared__ __align__(16) short As[6*64*64];     // 48 KB: A rows, K=384
  __shared__ __align__(16) short Bs[2*128*64];    // 32 KB: B K-slice dbuf
  __shared__ float lval[64*64];                   // 16 KB candidate vals
  __shared__ int   lidx[64*64];                   // 16 KB candidate cols
  __shared__ float rmax[64];
  __shared__ int   cnt[64];

  const int t = threadIdx.x;
  const int bid = blockIdx.x;
  // XCD grouping: 2 XCDs per batch -> per-XCD e2 working set 3.15MB fits 4MB L2
  const int xcd = bid & 7, slot = bid >> 3;
  const int batch = xcd >> 1;
  const int rowblk = (xcd & 1)*32 + slot;
  const int m0g = batch*NN + rowblk*64;

  const unsigned short* ap = e1x + (size_t)m0g*384;
  const unsigned short* bp = e2x + (size_t)batch*NN*384;
  const float* Vb = Vf + (size_t)batch*NN*CCH;

  const int wid = t>>6, lane = t&63;
  const int fr = lane&15, fq = lane>>4;
  const int r32 = t>>3, seg = t&7;
  const int w16 = wid*16;
  const int x7 = fr & 7;

  if (t < 64){ rmax[t] = -1e30f; cnt[t] = 0; }

  // stage A (all K=384), linear LDS dest (lane x 16B), pre-swizzled source
#pragma unroll
  for (int sl=0; sl<6; sl++){
#pragma unroll
    for (int i=0;i<2;i++){
      const int rowL = r32 + i*32;
      const int sw = (seg ^ (rowL&7))*8;
      gl_lds16(ap + (size_t)rowL*384 + sl*64 + sw, &As[sl*4096 + rowL*64 + seg*8]);
    }
  }
  // stage B tile 0, slice 0
#pragma unroll
  for (int i=0;i<4;i++){
    const int rowL = r32 + i*32;
    const int sw = (seg ^ (rowL&7))*8;
    gl_lds16(bp + (size_t)rowL*384 + sw, &Bs[rowL*64 + seg*8]);
  }
  __syncthreads();

  f32x4 acc[8];
#pragma unroll
  for (int n=0;n<8;n++) acc[n] = (f32x4){0.f,0.f,0.f,0.f};

  int buf = 0;
  for (int nt=0; nt<32; nt++){
#pragma unroll
    for (int sl=0; sl<6; sl++){
      // issue next stage early
      if (!(nt==31 && sl==5)){
        const int nnt = (sl==5) ? nt+1 : nt;
        const int nsl = (sl==5) ? 0 : sl+1;
        const unsigned short* bpt = bp + (size_t)nnt*128*384 + nsl*64;
        short* Bd = &Bs[(buf^1)*8192];
#pragma unroll
        for (int i=0;i<4;i++){
          const int rowL = r32 + i*32;
          const int sw = (seg ^ (rowL&7))*8;
          gl_lds16(bpt + (size_t)rowL*384 + sw, &Bd[rowL*64 + seg*8]);
        }
      }
      // compute slice: wave owns 16 rows x 128 cols
      {
        const short* Bc = &Bs[buf*8192];
        bf16x8 af[2];
        const int ar_ = w16 + fr;
#pragma unroll
        for (int ks=0;ks<2;ks++)
          af[ks] = *(const bf16x8*)&As[sl*4096 + ar_*64 + (((ks*4+fq) ^ x7)*8)];
#pragma unroll
        for (int n=0;n<8;n++){
          const int br_ = n*16 + fr;
#pragma unroll
          for (int ks=0;ks<2;ks++){
            bf16x8 bfv = *(const bf16x8*)&Bc[br_*64 + (((ks*4+fq) ^ x7)*8)];
            acc[n] = __builtin_amdgcn_mfma_f32_16x16x32_bf16(af[ks], bfv, acc[n], 0,0,0);
          }
        }
      }
      if (sl == 5){
        const int n0 = nt*128;
        // merge tile candidates into per-row lists (ballot-prefix, deterministic)
#pragma unroll
        for (int reg=0;reg<4;reg++){
          const int row_l = w16 + fq*4 + reg;
          float m = acc[0][reg];
#pragma unroll
          for (int n=1;n<8;n++) m = fmaxf(m, acc[n][reg]);
#pragma unroll
          for (int off=1;off<16;off<<=1) m = fmaxf(m, __shfl_xor(m, off));
          const float old = rmax[row_l];
          const float nm = fmaxf(old, m);
          const float th = nm - 1.0f;
          int c = cnt[row_l];
          if (nm > old){
            if (fr == 0) rmax[row_l] = nm;
            int w = 0;
            for (int q0=0; q0<c; q0+=16){
              const int q = q0 + fr;
              float vv = 0.f; int vi = 0; bool keep = false;
              if (q < c){ vv = lval[row_l*64+q]; vi = lidx[row_l*64+q]; keep = vv > th; }
              unsigned long long bal = __ballot(keep);
              const unsigned s16 = (unsigned)(bal >> (fq*16)) & 0xFFFFu;
              const int pos = w + __popc(s16 & ((1u<<fr)-1u));
              if (keep){ lval[row_l*64+pos] = vv; lidx[row_l*64+pos] = vi; }
              w += __popc(s16);
            }
            c = w;
          }
#pragma unroll
          for (int n=0;n<8;n++){
            const float val = acc[n][reg];
            const bool cond = val > th;
            unsigned long long bal = __ballot(cond);
            const unsigned s16 = (unsigned)(bal >> (fq*16)) & 0xFFFFu;
            const int pos = c + __popc(s16 & ((1u<<fr)-1u));
            if (cond && pos < 64){
              lval[row_l*64+pos] = val;
              lidx[row_l*64+pos] = n0 + n*16 + fr;
            }
            c += __popc(s16);
          }
          if (fr == 0) cnt[row_l] = (c < 64) ? c : 64;
        }
#pragma unroll
        for (int n=0;n<8;n++) acc[n] = (f32x4){0.f,0.f,0.f,0.f};
      }
      __syncthreads();
      buf ^= 1;
    }
  }

  // exact Michelot per row over candidate list (16-lane group per row)
#pragma unroll
  for (int reg=0;reg<4;reg++){
    const int row_l = w16 + fq*4 + reg;
    const int c = cnt[row_l];
    const float rm = rmax[row_l];
    float ev[4]; int ei[4];
#pragma unroll
    for (int j=0;j<4;j++){
      const int q = j*16 + fr;
      if (q < c){ ev[j] = lval[row_l*64+q]; ei[j] = lidx[row_l*64+q]; }
      else      { ev[j] = -1e30f; ei[j] = 0; }
    }
    float tau = rm - 1.0f;
    int prev = -1;
    for (int it=0; it<32; ++it){
      float s = 0.f; int k = 0;
#pragma unroll
      for (int j=0;j<4;j++) if (ev[j] > tau){ s += ev[j]; k++; }
#pragma unroll
      for (int off=1;off<16;off<<=1){ s += __shfl_xor(s, off); k += __shfl_xor(k, off); }
      const float tn = (s - 1.f)/(float)k;
      if (k == prev) break;
      prev = k; tau = tn;
    }
    int w2 = 0;
#pragma unroll
    for (int j=0;j<4;j++){
      const int q = j*16 + fr;
      const float p = ev[j] - tau;
      const bool nz = (q < c) && (p > 0.f);
      unsigned long long bal = __ballot(nz);
      const unsigned s16 = (unsigned)(bal >> (fq*16)) & 0xFFFFu;
      const int pos = w2 + __popc(s16 & ((1u<<fr)-1u));
      if (nz){ lval[row_l*64+pos] = p; lidx[row_l*64+pos] = ei[j]; }
      w2 += __popc(s16);
    }
    if (fr == 0) cnt[row_l] = w2;
  }
  __syncthreads();

  // sparse PV + residual: thread t owns channel t
  const float* xb = xr + (size_t)m0g*CCH;
  float* ob = out + (size_t)m0g*CCH;
  for (int r=0;r<64;r++){
    float a = xb[(size_t)r*CCH + t];
    const int c = cnt[r];
    for (int q=0;q<c;q++){
      const float p = lval[r*64+q];
      const int ix = lidx[r*64+q];
      a = fmaf(p, Vb[(size_t)ix*CCH + t], a);
    }
    ob[(size_t)r*CCH + t] = a;
  }
}

extern "C" void kernel_launch(void* const* d_in, const int* in_sizes, int n_in,
                              void* d_out, int out_size, void* d_ws, size_t ws_size,
                              hipStream_t stream) {
  const float* x  = (const float*)d_in[0];
  const float* W1 = (const float*)d_in[1];
  const float* b1 = (const float*)d_in[2];
  const float* a1 = (const float*)d_in[3];
  const float* W2 = (const float*)d_in[4];
  const float* b2 = (const float*)d_in[5];
  const float* a2 = (const float*)d_in[6];
  const float* Wa = (const float*)d_in[7];
  const float* ba = (const float*)d_in[8];
  const float* aa = (const float*)d_in[9];
  float* out = (float*)d_out;

  // ws: xs 25.2MB | Wt 0.8MB | e1x 12.6MB | e2x 12.6MB | V 16.8MB  (~68MB, no S)
  unsigned short* xs  = (unsigned short*)d_ws;
  unsigned short* Wt  = xs  + (size_t)16384*768;
  unsigned short* e1x = Wt  + (size_t)512*768;
  unsigned short* e2x = e1x + (size_t)16384*384;
  float* Vf = (float*)(e2x + (size_t)16384*384);

  dim3 blk(256);
  prep_x<<<dim3(2048,1,1), blk, 0, stream>>>(x, xs);
  prep_w<<<dim3(512,1,1), blk, 0, stream>>>(W1, W2, Wa, Wt);
  proj_mfma<<<dim3(4,256,1), blk, 0, stream>>>(xs, Wt, b1,a1, b2,a2, ba,aa,
                                               e1x, e2x, Vf);
  flash_spv<<<dim3(256,1,1), blk, 0, stream>>>(e1x, e2x, Vf, x, out);
}

// Round 12
// 173.252 us; speedup vs baseline: 1.5293x; 1.5293x over previous
//
#include <hip/hip_runtime.h>
#include <cstdint>

#define BB 4
#define NN 4096
#define CCH 256
#define CAP 256

typedef __attribute__((ext_vector_type(8))) short bf16x8;
typedef __attribute__((ext_vector_type(4))) float f32x4;

__device__ __forceinline__ unsigned short bf16rn(float f){
  unsigned u = __float_as_uint(f);
  unsigned r = u + 0x7FFFu + ((u>>16)&1u);
  return (unsigned short)(r>>16);
}
__device__ __forceinline__ float bf16tof(unsigned short h){
  return __uint_as_float(((unsigned)h)<<16);
}
__device__ __forceinline__ void gl_lds16(const void* g, void* l){
  __builtin_amdgcn_global_load_lds(
    (const __attribute__((address_space(1))) void*)g,
    (__attribute__((address_space(3))) void*)l, 16, 0, 0);
}

// ---- prep: split x -> xs [16384][768] bf16 (hi | lo | hi) ----
__global__ __launch_bounds__(256) void prep_x(
    const float* __restrict__ x, unsigned short* __restrict__ xs)
{
  const int stride = gridDim.x * 256;
  for (int idx = blockIdx.x*256 + threadIdx.x; idx < 16384*64; idx += stride){
    const int r = idx >> 6, c4 = (idx & 63) * 4;
    float4 u = *(const float4*)(x + (size_t)r*256 + c4);
    ushort4 h, l;
    h.x=bf16rn(u.x); l.x=bf16rn(u.x - bf16tof(h.x));
    h.y=bf16rn(u.y); l.y=bf16rn(u.y - bf16tof(h.y));
    h.z=bf16rn(u.z); l.z=bf16rn(u.z - bf16tof(h.z));
    h.w=bf16rn(u.w); l.w=bf16rn(u.w - bf16tof(h.w));
    unsigned short* row = xs + (size_t)r*768;
    *(ushort4*)(row + c4)       = h;
    *(ushort4*)(row + 256 + c4) = l;
    *(ushort4*)(row + 512 + c4) = h;
  }
}

// ---- prep: weights -> Wt [512][768] bf16 (hi | hi | lo) ----
__global__ __launch_bounds__(256) void prep_w(
    const float* __restrict__ W1, const float* __restrict__ W2,
    const float* __restrict__ Wa, unsigned short* __restrict__ Wt)
{
  const int n = blockIdx.x;      // 512
  const int k = threadIdx.x;     // 256
  float w = (n < 128) ? W1[(size_t)k*128 + n]
          : (n < 256) ? W2[(size_t)k*128 + (n-128)]
                      : Wa[(size_t)k*256 + (n-256)];
  unsigned short h = bf16rn(w);
  unsigned short l = bf16rn(w - bf16tof(h));
  unsigned short* row = Wt + (size_t)n*768;
  row[k] = h; row[256+k] = h; row[512+k] = l;
}

// ---- fused projection GEMM: 64x128 tile, K=768, single-buffer, XCD-swizzled ----
__global__ __launch_bounds__(256) void proj_mfma(
    const unsigned short* __restrict__ xs, const unsigned short* __restrict__ Wt,
    const float* __restrict__ b1, const float* __restrict__ a1,
    const float* __restrict__ b2, const float* __restrict__ a2,
    const float* __restrict__ ba, const float* __restrict__ aa,
    unsigned short* __restrict__ e1x, unsigned short* __restrict__ e2x,
    float* __restrict__ Vf)
{
  __shared__ __align__(16) short As[64*64];
  __shared__ __align__(16) short Bs[128*64];
  const int t = threadIdx.x;
  const int bid = blockIdx.y * 4 + blockIdx.x;
  const int W = (bid & 7) * 128 + (bid >> 3);
  const int bx = W & 3, by = W >> 2;
  const int m0 = by*64, n0 = bx*128;
  const int wid = t>>6, lane = t&63;
  const int wr = wid>>1, wc = wid&1;
  const int fr = lane&15, fq = lane>>4;
  const int r32 = t>>3, seg = t&7;

  const unsigned short* ap = xs + (size_t)m0*768;
  const unsigned short* bp = Wt + (size_t)n0*768;

  f32x4 acc[2][4];
#pragma unroll
  for (int m=0;m<2;m++)
#pragma unroll
    for (int n=0;n<4;n++) acc[m][n] = (f32x4){0.f,0.f,0.f,0.f};

#pragma unroll
  for (int s=0;s<12;s++){
    const int kk = s*64;
#pragma unroll
    for (int i=0;i<2;i++){
      const int rowL = r32 + i*32;
      const int sw = (seg ^ (rowL & 7)) * 8;
      gl_lds16(ap + (size_t)rowL*768 + kk + sw, &As[rowL*64 + seg*8]);
    }
#pragma unroll
    for (int i=0;i<4;i++){
      const int rowL = r32 + i*32;
      const int sw = (seg ^ (rowL & 7)) * 8;
      gl_lds16(bp + (size_t)rowL*768 + kk + sw, &Bs[rowL*64 + seg*8]);
    }
    __syncthreads();
    bf16x8 af[2][2], bf[4][2];
#pragma unroll
    for (int m=0;m<2;m++){
      const int ar_ = wr*32 + m*16 + fr;
#pragma unroll
      for (int ks=0;ks<2;ks++)
        af[m][ks] = *(const bf16x8*)&As[ar_*64 + (((ks*4+fq) ^ (ar_&7))*8)];
    }
#pragma unroll
    for (int n=0;n<4;n++){
      const int br_ = wc*64 + n*16 + fr;
#pragma unroll
      for (int ks=0;ks<2;ks++)
        bf[n][ks] = *(const bf16x8*)&Bs[br_*64 + (((ks*4+fq) ^ (br_&7))*8)];
    }
#pragma unroll
    for (int m=0;m<2;m++)
#pragma unroll
      for (int n=0;n<4;n++)
#pragma unroll
        for (int ks=0;ks<2;ks++)
          acc[m][n] = __builtin_amdgcn_mfma_f32_16x16x32_bf16(af[m][ks], bf[n][ks], acc[m][n], 0,0,0);
    __syncthreads();
  }

  if (bx < 2){
    const float* bb = bx ? b2 : b1;
    const float al = bx ? a2[0] : a1[0];
    unsigned short* ex = bx ? e2x : e1x;
#pragma unroll
    for (int m=0;m<2;m++){
#pragma unroll
      for (int n=0;n<4;n++){
        const int c = wc*64 + n*16 + fr;
        const float bias = bb[c];
#pragma unroll
        for (int reg=0;reg<4;reg++){
          const size_t r = (size_t)(m0 + wr*32 + m*16 + fq*4 + reg);
          float u = acc[m][n][reg] + bias;
          u = u >= 0.f ? u : al*u;
          unsigned short h = bf16rn(u);
          unsigned short l = bf16rn(u - bf16tof(h));
          if (bx == 0){            // e1x: [h | l | h]
            ex[r*384 + c] = h; ex[r*384 + 128 + c] = l; ex[r*384 + 256 + c] = h;
          } else {                 // e2x: [h | h | l]
            ex[r*384 + c] = h; ex[r*384 + 128 + c] = h; ex[r*384 + 256 + c] = l;
          }
        }
      }
    }
  } else {
    const float al = aa[0];
#pragma unroll
    for (int m=0;m<2;m++){
#pragma unroll
      for (int n=0;n<4;n++){
        const int c = (bx-2)*128 + wc*64 + n*16 + fr;
        const float bias = ba[c];
#pragma unroll
        for (int reg=0;reg<4;reg++){
          const size_t r = (size_t)(m0 + wr*32 + m*16 + fq*4 + reg);
          float u = acc[m][n][reg] + bias;
          Vf[r*CCH + c] = u >= 0.f ? u : al*u;
        }
      }
    }
  }
}

// ---- QK^T + per-(row,tile) max metadata; nt S stores; 2 batches/dispatch ----
__global__ __launch_bounds__(256) void qk_mfma(
    const unsigned short* __restrict__ e1base, const unsigned short* __restrict__ e2base,
    float* __restrict__ Sbase, float* __restrict__ Mg)
{
  __shared__ __align__(16) short As[128*64];
  __shared__ __align__(16) short Bs[128*64];
  const int t = threadIdx.x;
  const int bid = (blockIdx.z * 32 + blockIdx.y) * 32 + blockIdx.x;
  const int W = (bid & 7) * 256 + (bid >> 3);
  const int bx = W & 31, by = (W >> 5) & 31, z = W >> 10;
  const int m0 = by*128, n0 = bx*128;
  const int wid = t>>6, lane = t&63;
  const int wr = wid>>1, wc = wid&1;
  const int fr = lane&15, fq = lane>>4;
  const int r32 = t>>3, seg = t&7;

  const unsigned short* ap = e1base + (size_t)z*NN*384 + (size_t)m0*384;
  const unsigned short* bp = e2base + (size_t)z*NN*384 + (size_t)n0*384;
  float* S = Sbase + (size_t)z*NN*NN;

  f32x4 acc[4][4];
#pragma unroll
  for (int m=0;m<4;m++)
#pragma unroll
    for (int n=0;n<4;n++) acc[m][n] = (f32x4){0.f,0.f,0.f,0.f};

#pragma unroll
  for (int s=0;s<6;s++){
    const int kk = s*64;
#pragma unroll
    for (int i=0;i<4;i++){
      const int rowL = r32 + i*32;
      const int sw = (seg ^ (rowL & 7)) * 8;
      gl_lds16(ap + (size_t)rowL*384 + kk + sw, &As[rowL*64 + seg*8]);
      gl_lds16(bp + (size_t)rowL*384 + kk + sw, &Bs[rowL*64 + seg*8]);
    }
    __syncthreads();
    bf16x8 af[4][2], bf[4][2];
#pragma unroll
    for (int m=0;m<4;m++){
      const int ar_ = wr*64 + m*16 + fr;
#pragma unroll
      for (int ks=0;ks<2;ks++)
        af[m][ks] = *(const bf16x8*)&As[ar_*64 + (((ks*4+fq) ^ (ar_&7))*8)];
    }
#pragma unroll
    for (int n=0;n<4;n++){
      const int br_ = wc*64 + n*16 + fr;
#pragma unroll
      for (int ks=0;ks<2;ks++)
        bf[n][ks] = *(const bf16x8*)&Bs[br_*64 + (((ks*4+fq) ^ (br_&7))*8)];
    }
#pragma unroll
    for (int m=0;m<4;m++)
#pragma unroll
      for (int n=0;n<4;n++)
#pragma unroll
        for (int ks=0;ks<2;ks++)
          acc[m][n] = __builtin_amdgcn_mfma_f32_16x16x32_bf16(af[m][ks], bf[n][ks], acc[m][n], 0,0,0);
    __syncthreads();
  }
  // S write (nontemporal: only ~2% re-read later)
#pragma unroll
  for (int m=0;m<4;m++){
#pragma unroll
    for (int n=0;n<4;n++){
#pragma unroll
      for (int reg=0;reg<4;reg++){
        const int r = m0 + wr*64 + m*16 + fq*4 + reg;
        const int c = n0 + wc*64 + n*16 + fr;
        __builtin_nontemporal_store(acc[m][n][reg], &S[(size_t)r*NN + c]);
      }
    }
  }
  // per-row tile max -> Mg[(z*NN + row)*32 + bx]  (reuse As as float scratch)
  float* Mh = (float*)As;
#pragma unroll
  for (int m=0;m<4;m++){
#pragma unroll
    for (int reg=0;reg<4;reg++){
      float mm = fmaxf(fmaxf(acc[m][0][reg],acc[m][1][reg]),
                       fmaxf(acc[m][2][reg],acc[m][3][reg]));
#pragma unroll
      for (int o=1;o<16;o<<=1) mm = fmaxf(mm, __shfl_xor(mm, o));
      if (fr == 0) Mh[(wr*64 + m*16 + fq*4 + reg)*2 + wc] = mm;
    }
  }
  __syncthreads();
  if (t < 128){
    const float vmax = fmaxf(Mh[t*2+0], Mh[t*2+1]);
    Mg[((size_t)z*NN + m0 + t)*32 + bx] = vmax;
  }
}

// ---- selective sparsemax + sparse PV: wave per row, reads only hot tiles ----
__global__ __launch_bounds__(256) void spv2(
    const float* __restrict__ S, const float* __restrict__ Mg,
    const float* __restrict__ V, const float* __restrict__ xr,
    float* __restrict__ out)
{
  __shared__ float lv[4][CAP];
  __shared__ int   li[4][CAP];
  const int t = threadIdx.x, wid = t>>6, lane = t&63;
  const int row = blockIdx.x*4 + wid;      // 0..8191 within pair
  const int z = row >> 12;
  const float* srow = S + (size_t)row*NN;
  const float* mrow = Mg + (size_t)row*32;

  // row max from tile maxes
  float mv = (lane < 32) ? mrow[lane] : -1e30f;
#pragma unroll
  for (int o=32;o;o>>=1) mv = fmaxf(mv, __shfl_xor(mv, o));
  const float th = mv - 1.0f;
  const bool q = (lane < 32) && (mrow[lane] > th);
  const unsigned long long qm = __ballot(q);

  // collect candidates {s > th} from qualifying tiles
  int cntw = 0;
  {
    unsigned long long rem = qm;
    while (rem){
      const int tile = __ffsll(rem) - 1; rem &= rem - 1;
      const float2 u = *(const float2*)&srow[tile*128 + lane*2];
      const bool c0 = u.x > th;
      unsigned long long b0 = __ballot(c0);
      int p0 = cntw + __popcll(b0 & ((1ULL<<lane)-1ULL));
      if (c0 && p0 < CAP){ lv[wid][p0] = u.x; li[wid][p0] = tile*128 + lane*2; }
      cntw += __popcll(b0);
      const bool c1 = u.y > th;
      unsigned long long b1 = __ballot(c1);
      int p1 = cntw + __popcll(b1 & ((1ULL<<lane)-1ULL));
      if (c1 && p1 < CAP){ lv[wid][p1] = u.y; li[wid][p1] = tile*128 + lane*2 + 1; }
      cntw += __popcll(b1);
    }
  }
  const bool ovf = cntw > CAP;

  float tau = th;
  int k = -1;
  if (!ovf){
    float ev[4]; int ei[4];
#pragma unroll
    for (int j=0;j<4;j++){
      const int qq = j*64 + lane;
      if (qq < cntw){ ev[j] = lv[wid][qq]; ei[j] = li[wid][qq]; }
      else          { ev[j] = -1e30f; ei[j] = 0; }
    }
    int prev = -1;
    for (int it=0; it<64; ++it){
      float s = 0.f; int kk = 0;
#pragma unroll
      for (int j=0;j<4;j++) if (ev[j] > tau){ s += ev[j]; kk++; }
#pragma unroll
      for (int o=32;o;o>>=1){ s += __shfl_xor(s,o); kk += __shfl_xor(kk,o); }
      const float tn = (s - 1.f)/(float)kk;
      if (kk == prev) break;
      prev = kk; tau = tn;
    }
    // compact positives (p, idx) into list
    int k2 = 0;
#pragma unroll
    for (int j=0;j<4;j++){
      const int qq = j*64 + lane;
      const float p = ev[j] - tau;
      const bool nz = (qq < cntw) && (p > 0.f);
      unsigned long long b = __ballot(nz);
      const int pos = k2 + __popcll(b & ((1ULL<<lane)-1ULL));
      if (nz){ lv[wid][pos] = p; li[wid][pos] = ei[j]; }
      k2 += __popcll(b);
    }
    k = k2;
  } else {
    // exact fallback: streaming Michelot over the full row
    int prev = -1;
    for (int it=0; it<64; ++it){
      float s = 0.f; int kk = 0;
      for (int c0=0; c0<NN; c0+=256){
        const float4 u = *(const float4*)&srow[c0 + lane*4];
        if (u.x > tau){ s += u.x; kk++; }
        if (u.y > tau){ s += u.y; kk++; }
        if (u.z > tau){ s += u.z; kk++; }
        if (u.w > tau){ s += u.w; kk++; }
      }
#pragma unroll
      for (int o=32;o;o>>=1){ s += __shfl_xor(s,o); kk += __shfl_xor(kk,o); }
      const float tn = (s - 1.f)/(float)kk;
      if (kk == prev) break;
      prev = kk; tau = tn;
    }
  }

  // sparse PV + residual: lane owns channels lane*4..+3
  const float* Vb = V + ((size_t)z << 12) * CCH;
  float4 a = *(const float4*)&xr[(size_t)row*CCH + lane*4];
  if (k >= 0){
    for (int qq=0; qq<k; ++qq){
      const float p = lv[wid][qq];
      const int ix = li[wid][qq];
      const float4 vv = *(const float4*)&Vb[(size_t)ix*CCH + lane*4];
      a.x = fmaf(p, vv.x, a.x); a.y = fmaf(p, vv.y, a.y);
      a.z = fmaf(p, vv.z, a.z); a.w = fmaf(p, vv.w, a.w);
    }
  } else {
    // chunked gather per qualifying tile (support still inside hot tiles)
    unsigned long long rem = qm;
    while (rem){
      const int tile = __ffsll(rem) - 1; rem &= rem - 1;
      const float2 u = *(const float2*)&srow[tile*128 + lane*2];
      int base = 0;
      const bool c0 = u.x > tau;
      unsigned long long b0 = __ballot(c0);
      int p0 = __popcll(b0 & ((1ULL<<lane)-1ULL));
      if (c0){ lv[wid][p0] = u.x - tau; li[wid][p0] = tile*128 + lane*2; }
      base = __popcll(b0);
      const bool c1 = u.y > tau;
      unsigned long long b1 = __ballot(c1);
      int p1 = base + __popcll(b1 & ((1ULL<<lane)-1ULL));
      if (c1){ lv[wid][p1] = u.y - tau; li[wid][p1] = tile*128 + lane*2 + 1; }
      base += __popcll(b1);
      for (int qq=0; qq<base; ++qq){
        const float p = lv[wid][qq];
        const int ix = li[wid][qq];
        const float4 vv = *(const float4*)&Vb[(size_t)ix*CCH + lane*4];
        a.x = fmaf(p, vv.x, a.x); a.y = fmaf(p, vv.y, a.y);
        a.z = fmaf(p, vv.z, a.z); a.w = fmaf(p, vv.w, a.w);
      }
    }
  }
  *(float4*)&out[(size_t)row*CCH + lane*4] = a;
}

extern "C" void kernel_launch(void* const* d_in, const int* in_sizes, int n_in,
                              void* d_out, int out_size, void* d_ws, size_t ws_size,
                              hipStream_t stream) {
  const float* x  = (const float*)d_in[0];
  const float* W1 = (const float*)d_in[1];
  const float* b1 = (const float*)d_in[2];
  const float* a1 = (const float*)d_in[3];
  const float* W2 = (const float*)d_in[4];
  const float* b2 = (const float*)d_in[5];
  const float* a2 = (const float*)d_in[6];
  const float* Wa = (const float*)d_in[7];
  const float* ba = (const float*)d_in[8];
  const float* aa = (const float*)d_in[9];
  float* out = (float*)d_out;

  // ws: xs 25.2MB | Wt 0.8MB | e1x 12.6MB | e2x 12.6MB | V 16.8MB | S2 134MB = 202MB
  unsigned short* xs  = (unsigned short*)d_ws;
  unsigned short* Wt  = xs  + (size_t)16384*768;
  unsigned short* e1x = Wt  + (size_t)512*768;
  unsigned short* e2x = e1x + (size_t)16384*384;
  float* Vf = (float*)(e2x + (size_t)16384*384);
  float* S2 = Vf + (size_t)BB*NN*CCH;
  float* Mg = (float*)xs;   // xs dead after proj_mfma; reuse for tile maxes (1MB)

  dim3 blk(256);
  prep_x<<<dim3(2048,1,1), blk, 0, stream>>>(x, xs);
  prep_w<<<dim3(512,1,1), blk, 0, stream>>>(W1, W2, Wa, Wt);
  proj_mfma<<<dim3(4,256,1), blk, 0, stream>>>(xs, Wt, b1,a1, b2,a2, ba,aa,
                                               e1x, e2x, Vf);
  for (int pair=0;pair<2;pair++){
    const size_t eo = (size_t)pair*2*NN*384;
    const size_t co = (size_t)pair*2*NN*CCH;
    qk_mfma<<<dim3(32,32,2), blk, 0, stream>>>(e1x + eo, e2x + eo, S2, Mg);
    spv2<<<dim3(2048,1,1), blk, 0, stream>>>(S2, Mg, Vf + co, x + co, out + co);
  }
}

// Round 15
// 156.458 us; speedup vs baseline: 1.6934x; 1.1073x over previous
//
#include <hip/hip_runtime.h>
#include <cstdint>

#define BB 4
#define NN 4096
#define CCH 256
#define CAP 256

typedef __attribute__((ext_vector_type(8))) short bf16x8;
typedef __attribute__((ext_vector_type(4))) float f32x4;

__device__ __forceinline__ unsigned short bf16rn(float f){
  unsigned u = __float_as_uint(f);
  unsigned r = u + 0x7FFFu + ((u>>16)&1u);
  return (unsigned short)(r>>16);
}
__device__ __forceinline__ float bf16tof(unsigned short h){
  return __uint_as_float(((unsigned)h)<<16);
}
__device__ __forceinline__ void gl_lds16(const void* g, void* l){
  __builtin_amdgcn_global_load_lds(
    (const __attribute__((address_space(1))) void*)g,
    (__attribute__((address_space(3))) void*)l, 16, 0, 0);
}

// ---- prep: split x -> xs [16384][768] bf16 (hi | lo | hi) ----
__global__ __launch_bounds__(256) void prep_x(
    const float* __restrict__ x, unsigned short* __restrict__ xs)
{
  const int stride = gridDim.x * 256;
  for (int idx = blockIdx.x*256 + threadIdx.x; idx < 16384*64; idx += stride){
    const int r = idx >> 6, c4 = (idx & 63) * 4;
    float4 u = *(const float4*)(x + (size_t)r*256 + c4);
    ushort4 h, l;
    h.x=bf16rn(u.x); l.x=bf16rn(u.x - bf16tof(h.x));
    h.y=bf16rn(u.y); l.y=bf16rn(u.y - bf16tof(h.y));
    h.z=bf16rn(u.z); l.z=bf16rn(u.z - bf16tof(h.z));
    h.w=bf16rn(u.w); l.w=bf16rn(u.w - bf16tof(h.w));
    unsigned short* row = xs + (size_t)r*768;
    *(ushort4*)(row + c4)       = h;
    *(ushort4*)(row + 256 + c4) = l;
    *(ushort4*)(row + 512 + c4) = h;
  }
}

// ---- prep: weights -> Wt [512][768] bf16 (hi | hi | lo) ----
__global__ __launch_bounds__(256) void prep_w(
    const float* __restrict__ W1, const float* __restrict__ W2,
    const float* __restrict__ Wa, unsigned short* __restrict__ Wt)
{
  const int n = blockIdx.x;      // 512
  const int k = threadIdx.x;     // 256
  float w = (n < 128) ? W1[(size_t)k*128 + n]
          : (n < 256) ? W2[(size_t)k*128 + (n-128)]
                      : Wa[(size_t)k*256 + (n-256)];
  unsigned short h = bf16rn(w);
  unsigned short l = bf16rn(w - bf16tof(h));
  unsigned short* row = Wt + (size_t)n*768;
  row[k] = h; row[256+k] = h; row[512+k] = l;
}

// ---- fused projection GEMM: 64x128 tile, K=768, single-buffer, XCD-swizzled ----
__global__ __launch_bounds__(256) void proj_mfma(
    const unsigned short* __restrict__ xs, const unsigned short* __restrict__ Wt,
    const float* __restrict__ b1, const float* __restrict__ a1,
    const float* __restrict__ b2, const float* __restrict__ a2,
    const float* __restrict__ ba, const float* __restrict__ aa,
    unsigned short* __restrict__ e1x, unsigned short* __restrict__ e2x,
    float* __restrict__ Vf)
{
  __shared__ __align__(16) short As[64*64];
  __shared__ __align__(16) short Bs[128*64];
  const int t = threadIdx.x;
  const int bid = blockIdx.y * 4 + blockIdx.x;
  const int W = (bid & 7) * 128 + (bid >> 3);
  const int bx = W & 3, by = W >> 2;
  const int m0 = by*64, n0 = bx*128;
  const int wid = t>>6, lane = t&63;
  const int wr = wid>>1, wc = wid&1;
  const int fr = lane&15, fq = lane>>4;
  const int r32 = t>>3, seg = t&7;

  const unsigned short* ap = xs + (size_t)m0*768;
  const unsigned short* bp = Wt + (size_t)n0*768;

  f32x4 acc[2][4];
#pragma unroll
  for (int m=0;m<2;m++)
#pragma unroll
    for (int n=0;n<4;n++) acc[m][n] = (f32x4){0.f,0.f,0.f,0.f};

#pragma unroll
  for (int s=0;s<12;s++){
    const int kk = s*64;
#pragma unroll
    for (int i=0;i<2;i++){
      const int rowL = r32 + i*32;
      const int sw = (seg ^ (rowL & 7)) * 8;
      gl_lds16(ap + (size_t)rowL*768 + kk + sw, &As[rowL*64 + seg*8]);
    }
#pragma unroll
    for (int i=0;i<4;i++){
      const int rowL = r32 + i*32;
      const int sw = (seg ^ (rowL & 7)) * 8;
      gl_lds16(bp + (size_t)rowL*768 + kk + sw, &Bs[rowL*64 + seg*8]);
    }
    __syncthreads();
    bf16x8 af[2][2], bf[4][2];
#pragma unroll
    for (int m=0;m<2;m++){
      const int ar_ = wr*32 + m*16 + fr;
#pragma unroll
      for (int ks=0;ks<2;ks++)
        af[m][ks] = *(const bf16x8*)&As[ar_*64 + (((ks*4+fq) ^ (ar_&7))*8)];
    }
#pragma unroll
    for (int n=0;n<4;n++){
      const int br_ = wc*64 + n*16 + fr;
#pragma unroll
      for (int ks=0;ks<2;ks++)
        bf[n][ks] = *(const bf16x8*)&Bs[br_*64 + (((ks*4+fq) ^ (br_&7))*8)];
    }
#pragma unroll
    for (int m=0;m<2;m++)
#pragma unroll
      for (int n=0;n<4;n++)
#pragma unroll
        for (int ks=0;ks<2;ks++)
          acc[m][n] = __builtin_amdgcn_mfma_f32_16x16x32_bf16(af[m][ks], bf[n][ks], acc[m][n], 0,0,0);
    __syncthreads();
  }

  if (bx < 2){
    const float* bb = bx ? b2 : b1;
    const float al = bx ? a2[0] : a1[0];
    unsigned short* ex = bx ? e2x : e1x;
#pragma unroll
    for (int m=0;m<2;m++){
#pragma unroll
      for (int n=0;n<4;n++){
        const int c = wc*64 + n*16 + fr;
        const float bias = bb[c];
#pragma unroll
        for (int reg=0;reg<4;reg++){
          const size_t r = (size_t)(m0 + wr*32 + m*16 + fq*4 + reg);
          float u = acc[m][n][reg] + bias;
          u = u >= 0.f ? u : al*u;
          unsigned short h = bf16rn(u);
          unsigned short l = bf16rn(u - bf16tof(h));
          if (bx == 0){            // e1x: [h | l | h]
            ex[r*384 + c] = h; ex[r*384 + 128 + c] = l; ex[r*384 + 256 + c] = h;
          } else {                 // e2x: [h | h | l]
            ex[r*384 + c] = h; ex[r*384 + 128 + c] = h; ex[r*384 + 256 + c] = l;
          }
        }
      }
    }
  } else {
    const float al = aa[0];
#pragma unroll
    for (int m=0;m<2;m++){
#pragma unroll
      for (int n=0;n<4;n++){
        const int c = (bx-2)*128 + wc*64 + n*16 + fr;
        const float bias = ba[c];
#pragma unroll
        for (int reg=0;reg<4;reg++){
          const size_t r = (size_t)(m0 + wr*32 + m*16 + fq*4 + reg);
          float u = acc[m][n][reg] + bias;
          Vf[r*CCH + c] = u >= 0.f ? u : al*u;
        }
      }
    }
  }
}

// ---- QK^T -> fp16 delta S + fp32 tile-max M; all 4 batches; XCD-swizzled ----
__global__ __launch_bounds__(256) void qk_mfma(
    const unsigned short* __restrict__ e1base, const unsigned short* __restrict__ e2base,
    _Float16* __restrict__ S16, float* __restrict__ Mg)
{
  __shared__ __align__(16) short As[128*64];
  __shared__ __align__(16) short Bs[128*64];
  const int t = threadIdx.x;
  // nwg = 4096: each XCD takes 512 consecutive W (16 by-rows x 32 bx of one z)
  const int bid = (blockIdx.z * 32 + blockIdx.y) * 32 + blockIdx.x;
  const int W = (bid & 7) * 512 + (bid >> 3);
  const int bx = W & 31, by = (W >> 5) & 31, z = W >> 10;
  const int m0 = by*128, n0 = bx*128;
  const int wid = t>>6, lane = t&63;
  const int wr = wid>>1, wc = wid&1;
  const int fr = lane&15, fq = lane>>4;
  const int r32 = t>>3, seg = t&7;

  const unsigned short* ap = e1base + (size_t)z*NN*384 + (size_t)m0*384;
  const unsigned short* bp = e2base + (size_t)z*NN*384 + (size_t)n0*384;
  _Float16* S = S16 + (size_t)z*NN*NN;

  f32x4 acc[4][4];
#pragma unroll
  for (int m=0;m<4;m++)
#pragma unroll
    for (int n=0;n<4;n++) acc[m][n] = (f32x4){0.f,0.f,0.f,0.f};

#pragma unroll
  for (int s=0;s<6;s++){
    const int kk = s*64;
#pragma unroll
    for (int i=0;i<4;i++){
      const int rowL = r32 + i*32;
      const int sw = (seg ^ (rowL & 7)) * 8;
      gl_lds16(ap + (size_t)rowL*384 + kk + sw, &As[rowL*64 + seg*8]);
      gl_lds16(bp + (size_t)rowL*384 + kk + sw, &Bs[rowL*64 + seg*8]);
    }
    __syncthreads();
    bf16x8 af[4][2], bf[4][2];
#pragma unroll
    for (int m=0;m<4;m++){
      const int ar_ = wr*64 + m*16 + fr;
#pragma unroll
      for (int ks=0;ks<2;ks++)
        af[m][ks] = *(const bf16x8*)&As[ar_*64 + (((ks*4+fq) ^ (ar_&7))*8)];
    }
#pragma unroll
    for (int n=0;n<4;n++){
      const int br_ = wc*64 + n*16 + fr;
#pragma unroll
      for (int ks=0;ks<2;ks++)
        bf[n][ks] = *(const bf16x8*)&Bs[br_*64 + (((ks*4+fq) ^ (br_&7))*8)];
    }
#pragma unroll
    for (int m=0;m<4;m++)
#pragma unroll
      for (int n=0;n<4;n++)
#pragma unroll
        for (int ks=0;ks<2;ks++)
          acc[m][n] = __builtin_amdgcn_mfma_f32_16x16x32_bf16(af[m][ks], bf[n][ks], acc[m][n], 0,0,0);
    __syncthreads();
  }

  // 1) per-row tile max (half-tiles in Mh, combined in Mc)
  float* Mh = (float*)As;        // 256 floats
  float* Mc = (float*)Bs;        // 128 floats
#pragma unroll
  for (int m=0;m<4;m++){
#pragma unroll
    for (int reg=0;reg<4;reg++){
      float mm = fmaxf(fmaxf(acc[m][0][reg],acc[m][1][reg]),
                       fmaxf(acc[m][2][reg],acc[m][3][reg]));
#pragma unroll
      for (int o=1;o<16;o<<=1) mm = fmaxf(mm, __shfl_xor(mm, o));
      if (fr == 0) Mh[(wr*64 + m*16 + fq*4 + reg)*2 + wc] = mm;
    }
  }
  __syncthreads();
  if (t < 128){
    const float vmax = fmaxf(Mh[t*2+0], Mh[t*2+1]);
    Mc[t] = vmax;
    Mg[((size_t)z*NN + m0 + t)*32 + bx] = vmax;
  }
  __syncthreads();
  // 2) store fp16 deltas (delta <= 0; max element stores exact 0)
#pragma unroll
  for (int m=0;m<4;m++){
#pragma unroll
    for (int reg=0;reg<4;reg++){
      const int rl = wr*64 + m*16 + fq*4 + reg;
      const float tm = Mc[rl];
      const size_t rb = (size_t)(m0 + rl)*NN + n0 + wc*64;
#pragma unroll
      for (int n=0;n<4;n++)
        S[rb + n*16 + fr] = (_Float16)(acc[m][n][reg] - tm);
    }
  }
}

// ---- selective sparsemax + sparse PV over fp16-delta S; wave per row ----
__global__ __launch_bounds__(256) void spv2(
    const _Float16* __restrict__ S16, const float* __restrict__ Mg,
    const float* __restrict__ V, const float* __restrict__ xr,
    float* __restrict__ out)
{
  __shared__ float lv[4][CAP];
  __shared__ int   li[4][CAP];
  const int t = threadIdx.x, wid = t>>6, lane = t&63;
  const int row = blockIdx.x*4 + wid;      // 0..16383
  const int z = row >> 12;
  const _Float16* srow = S16 + (size_t)row*NN;
  const float* mrow = Mg + (size_t)row*32;

  // row max from tile maxes
  float mv = (lane < 32) ? mrow[lane] : -1e30f;
#pragma unroll
  for (int o=32;o;o>>=1) mv = fmaxf(mv, __shfl_xor(mv, o));
  const float th = mv - 1.0f;
  const bool q = (lane < 32) && (mrow[lane] > th);
  const unsigned long long qm = __ballot(q);

  // collect candidates {s > th} from qualifying tiles (s = tilemax + delta)
  int cntw = 0;
  {
    unsigned long long rem = qm;
    while (rem){
      const int tile = __ffsll(rem) - 1; rem &= rem - 1;
      const float tm = mrow[tile];
      const float s0 = tm + (float)srow[tile*128 + lane*2];
      const float s1 = tm + (float)srow[tile*128 + lane*2 + 1];
      const bool c0 = s0 > th;
      unsigned long long b0 = __ballot(c0);
      int p0 = cntw + __popcll(b0 & ((1ULL<<lane)-1ULL));
      if (c0 && p0 < CAP){ lv[wid][p0] = s0; li[wid][p0] = tile*128 + lane*2; }
      cntw += __popcll(b0);
      const bool c1 = s1 > th;
      unsigned long long b1 = __ballot(c1);
      int p1 = cntw + __popcll(b1 & ((1ULL<<lane)-1ULL));
      if (c1 && p1 < CAP){ lv[wid][p1] = s1; li[wid][p1] = tile*128 + lane*2 + 1; }
      cntw += __popcll(b1);
    }
  }
  const bool ovf = cntw > CAP;

  float tau = th;
  int k = -1;
  if (!ovf){
    float ev[4]; int ei[4];
#pragma unroll
    for (int j=0;j<4;j++){
      const int qq = j*64 + lane;
      if (qq < cntw){ ev[j] = lv[wid][qq]; ei[j] = li[wid][qq]; }
      else          { ev[j] = -1e30f; ei[j] = 0; }
    }
    int prev = -1;
    for (int it=0; it<64; ++it){
      float s = 0.f; int kk = 0;
#pragma unroll
      for (int j=0;j<4;j++) if (ev[j] > tau){ s += ev[j]; kk++; }
#pragma unroll
      for (int o=32;o;o>>=1){ s += __shfl_xor(s,o); kk += __shfl_xor(kk,o); }
      const float tn = (s - 1.f)/(float)kk;
      if (kk == prev) break;
      prev = kk; tau = tn;
    }
    // compact positives (p, idx)
    int k2 = 0;
#pragma unroll
    for (int j=0;j<4;j++){
      const int qq = j*64 + lane;
      const float p = ev[j] - tau;
      const bool nz = (qq < cntw) && (p > 0.f);
      unsigned long long b = __ballot(nz);
      const int pos = k2 + __popcll(b & ((1ULL<<lane)-1ULL));
      if (nz){ lv[wid][pos] = p; li[wid][pos] = ei[j]; }
      k2 += __popcll(b);
    }
    k = k2;
  } else {
    // exact fallback: streaming Michelot over the full reconstructed row
    int prev = -1;
    for (int it=0; it<64; ++it){
      float s = 0.f; int kk = 0;
      for (int tile=0; tile<32; ++tile){
        const float tm = mrow[tile];
        const float s0 = tm + (float)srow[tile*128 + lane*2];
        const float s1 = tm + (float)srow[tile*128 + lane*2 + 1];
        if (s0 > tau){ s += s0; kk++; }
        if (s1 > tau){ s += s1; kk++; }
      }
#pragma unroll
      for (int o=32;o;o>>=1){ s += __shfl_xor(s,o); kk += __shfl_xor(kk,o); }
      const float tn = (s - 1.f)/(float)kk;
      if (kk == prev) break;
      prev = kk; tau = tn;
    }
  }

  // sparse PV + residual: lane owns channels lane*4..+3
  const float* Vb = V + ((size_t)z << 12) * CCH;
  float4 a = *(const float4*)&xr[(size_t)row*CCH + lane*4];
  if (k >= 0){
    for (int qq=0; qq<k; ++qq){
      const float p = lv[wid][qq];
      const int ix = li[wid][qq];
      const float4 vv = *(const float4*)&Vb[(size_t)ix*CCH + lane*4];
      a.x = fmaf(p, vv.x, a.x); a.y = fmaf(p, vv.y, a.y);
      a.z = fmaf(p, vv.z, a.z); a.w = fmaf(p, vv.w, a.w);
    }
  } else {
    unsigned long long rem = qm;
    while (rem){
      const int tile = __ffsll(rem) - 1; rem &= rem - 1;
      const float tm = mrow[tile];
      const float s0 = tm + (float)srow[tile*128 + lane*2];
      const float s1 = tm + (float)srow[tile*128 + lane*2 + 1];
      int base = 0;
      const bool c0 = s0 > tau;
      unsigned long long b0 = __ballot(c0);
      int p0 = __popcll(b0 & ((1ULL<<lane)-1ULL));
      if (c0){ lv[wid][p0] = s0 - tau; li[wid][p0] = tile*128 + lane*2; }
      base = __popcll(b0);
      const bool c1 = s1 > tau;
      unsigned long long b1 = __ballot(c1);
      int p1 = base + __popcll(b1 & ((1ULL<<lane)-1ULL));
      if (c1){ lv[wid][p1] = s1 - tau; li[wid][p1] = tile*128 + lane*2 + 1; }
      base += __popcll(b1);
      for (int qq=0; qq<base; ++qq){
        const float p = lv[wid][qq];
        const int ix = li[wid][qq];
        const float4 vv = *(const float4*)&Vb[(size_t)ix*CCH + lane*4];
        a.x = fmaf(p, vv.x, a.x); a.y = fmaf(p, vv.y, a.y);
        a.z = fmaf(p, vv.z, a.z); a.w = fmaf(p, vv.w, a.w);
      }
    }
  }
  *(float4*)&out[(size_t)row*CCH + lane*4] = a;
}

extern "C" void kernel_launch(void* const* d_in, const int* in_sizes, int n_in,
                              void* d_out, int out_size, void* d_ws, size_t ws_size,
                              hipStream_t stream) {
  const float* x  = (const float*)d_in[0];
  const float* W1 = (const float*)d_in[1];
  const float* b1 = (const float*)d_in[2];
  const float* a1 = (const float*)d_in[3];
  const float* W2 = (const float*)d_in[4];
  const float* b2 = (const float*)d_in[5];
  const float* a2 = (const float*)d_in[6];
  const float* Wa = (const float*)d_in[7];
  const float* ba = (const float*)d_in[8];
  const float* aa = (const float*)d_in[9];
  float* out = (float*)d_out;

  // ws: xs 25.2MB | Wt 0.8MB | e1x 12.6MB | e2x 12.6MB | V 16.8MB | S16 134MB = 202MB
  unsigned short* xs  = (unsigned short*)d_ws;
  unsigned short* Wt  = xs  + (size_t)16384*768;
  unsigned short* e1x = Wt  + (size_t)512*768;
  unsigned short* e2x = e1x + (size_t)16384*384;
  float* Vf = (float*)(e2x + (size_t)16384*384);
  _Float16* S16 = (_Float16*)(Vf + (size_t)BB*NN*CCH);
  float* Mg = (float*)xs;   // xs dead after proj_mfma; tile maxes 2MB

  dim3 blk(256);
  prep_x<<<dim3(2048,1,1), blk, 0, stream>>>(x, xs);
  prep_w<<<dim3(512,1,1), blk, 0, stream>>>(W1, W2, Wa, Wt);
  proj_mfma<<<dim3(4,256,1), blk, 0, stream>>>(xs, Wt, b1,a1, b2,a2, ba,aa,
                                               e1x, e2x, Vf);
  qk_mfma<<<dim3(32,32,4), blk, 0, stream>>>(e1x, e2x, S16, Mg);
  spv2<<<dim3(4096,1,1), blk, 0, stream>>>(S16, Mg, Vf, x, out);
}